// Round 12
// baseline (468.156 us; speedup 1.0000x reference)
//
#include <hip/hip_runtime.h>
#include <math.h>

#define N_NODES 50000
#define N_EDGES 800000
#define EMBED 256
#define HID 128
#define OUTD 12
#define N_TGT 4096

#define SCAN_NB 196   // ceil(50000/256)
#define NPART 8       // XCD count; blockIdx&7 ~ XCD id (round-robin dispatch)
#define NODES_PER_PART 6250  // 50000/8
#define GB 256        // mega-kernel grid (1 block/CU -> co-residency guaranteed)

typedef short bf16x8 __attribute__((ext_vector_type(8)));
typedef float f32x4 __attribute__((ext_vector_type(4)));

// f32 -> bf16 round-to-nearest-even (bit-exact, deterministic)
__device__ __forceinline__ unsigned short f2b(float f) {
    union { float f; unsigned int u; } v;
    v.f = f;
    unsigned int u = v.u;
    return (unsigned short)((u + 0x7FFFu + ((u >> 16) & 1u)) >> 16);
}

__device__ __forceinline__ float b2f(unsigned short s) {
    union { unsigned int u; float f; } v;
    v.u = ((unsigned int)s) << 16;
    return v.f;
}

// ---------------- zero prelude (counts + barrier vars) ----------------
__global__ void k_zero0(int* __restrict__ counts, int* __restrict__ bar) {
    int i = blockIdx.x * 256 + threadIdx.x;
    if (i < N_NODES) counts[i] = 0;
    if (i < 2) bar[i] = 0;
}

// ---------------- device-scope grid barrier (generation counter) ----------------
// All GB blocks are co-resident (1 block/CU, tiny LDS/VGPR) -> no deadlock.
__device__ __forceinline__ void gbar(int* cnt, int* gen) {
    __syncthreads();
    if (threadIdx.x == 0) {
        int g = __hip_atomic_load(gen, __ATOMIC_RELAXED, __HIP_MEMORY_SCOPE_AGENT);
        __threadfence();
        int a = __hip_atomic_fetch_add(cnt, 1, __ATOMIC_ACQ_REL, __HIP_MEMORY_SCOPE_AGENT);
        if (a == GB - 1) {
            __hip_atomic_store(cnt, 0, __ATOMIC_RELAXED, __HIP_MEMORY_SCOPE_AGENT);
            __hip_atomic_fetch_add(gen, 1, __ATOMIC_ACQ_REL, __HIP_MEMORY_SCOPE_AGENT);
        } else {
            while (__hip_atomic_load(gen, __ATOMIC_ACQUIRE, __HIP_MEMORY_SCOPE_AGENT) == g) {}
        }
        __threadfence();
    }
    __syncthreads();
}

// ---------------- fused CSR build: conv+hist | scan | fill | sort ----------------
__global__ __launch_bounds__(256) void k_csr(const int* __restrict__ src,
                                             const int* __restrict__ dst,
                                             int* __restrict__ counts,
                                             int* __restrict__ partials,
                                             int* __restrict__ rowptr,
                                             int* __restrict__ cursor,
                                             float* __restrict__ dinv,
                                             int* __restrict__ col,
                                             const float* __restrict__ W1,
                                             unsigned short* __restrict__ Wt1,
                                             const float* __restrict__ W2,
                                             unsigned short* __restrict__ Wt2,
                                             int* __restrict__ bcnt, int* __restrict__ bgen) {
    __shared__ int smem[256];
    const int b = blockIdx.x, t = threadIdx.x;
    const int gtid = b * 256 + t;

    // ---- P1: weight conversion (independent) + XCD-partitioned histogram ----
    if (gtid < 32768) {                       // Wt1: 128 x 256
        int nn = gtid >> 8, k = gtid & 255;
        Wt1[nn * 256 + k] = f2b(W1[(size_t)k * 128 + nn]);
    } else if (gtid < 49152) {                // Wt2: 128 x 128
        int j = gtid - 32768;
        int nn = j >> 7, k = j & 127;
        Wt2[nn * 128 + k] = f2b(W2[(size_t)k * 128 + nn]);
    }
    {
        int g = b & (NPART - 1);
        int c = b >> 3;
#pragma unroll 4
        for (int e = c * 256 + t; e < N_EDGES; e += (GB / NPART) * 256) {
            int d = dst[e];
            if ((unsigned)(d - g * NODES_PER_PART) < (unsigned)NODES_PER_PART)
                atomicAdd(&counts[d], 1);
        }
    }
    gbar(bcnt, bgen);

    // ---- P2: per-segment sums ----
    if (b < SCAN_NB) {
        int i = b * 256 + t;
        int v = (i < N_NODES) ? counts[i] : 0;
#pragma unroll
        for (int off = 32; off > 0; off >>= 1) v += __shfl_down(v, off);
        if ((t & 63) == 0) smem[t >> 6] = v;
        __syncthreads();
        if (t == 0) partials[b] = smem[0] + smem[1] + smem[2] + smem[3];
    }
    gbar(bcnt, bgen);

    // ---- P3: top-level exclusive scan of 196 partials (block 0) ----
    if (b == 0) {
        int v = (t < SCAN_NB) ? partials[t] : 0;
        smem[t] = v;
        __syncthreads();
#pragma unroll
        for (int off = 1; off < 256; off <<= 1) {
            int x = (t >= off) ? smem[t - off] : 0;
            __syncthreads();
            smem[t] += x;
            __syncthreads();
        }
        if (t < SCAN_NB) partials[t] = smem[t] - v;  // exclusive
    }
    gbar(bcnt, bgen);

    // ---- P4: per-segment exclusive scan -> rowptr, cursor, dinv ----
    if (b < SCAN_NB) {
        int i = b * 256 + t;
        int c = (i < N_NODES) ? counts[i] : 0;
        smem[t] = c;
        __syncthreads();
#pragma unroll
        for (int off = 1; off < 256; off <<= 1) {
            int x = (t >= off) ? smem[t - off] : 0;
            __syncthreads();
            smem[t] += x;
            __syncthreads();
        }
        if (i < N_NODES) {
            int rp = partials[b] + smem[t] - c;  // exclusive
            rowptr[i] = rp;
            cursor[i] = rp;
            dinv[i] = rsqrtf(1.0f + (float)c);
        }
    }
    gbar(bcnt, bgen);

    // ---- P5: XCD-partitioned fill ----
    {
        int g = b & (NPART - 1);
        int c = b >> 3;
#pragma unroll 4
        for (int e = c * 256 + t; e < N_EDGES; e += (GB / NPART) * 256) {
            int d = dst[e];
            if ((unsigned)(d - g * NODES_PER_PART) < (unsigned)NODES_PER_PART) {
                int pos = atomicAdd(&cursor[d], 1);
                col[pos] = src[e];
            }
        }
    }
    gbar(bcnt, bgen);

    // ---- P6: per-row bitonic sort (determinism canonicalizer) ----
    {
        int wid = t >> 6, lane = t & 63;
        for (int v = b * 4 + wid; v < N_NODES; v += GB * 4) {
            int beg = rowptr[v], cnt = counts[v];
            if (cnt <= 1) continue;
            if (cnt <= 64) {
                int key = (lane < cnt) ? col[beg + lane] : 0x7FFFFFFF;
#pragma unroll
                for (int k = 2; k <= 64; k <<= 1) {
#pragma unroll
                    for (int j = k >> 1; j > 0; j >>= 1) {
                        int other = __shfl_xor(key, j);
                        bool up = ((lane & k) == 0);
                        bool lower = ((lane & j) == 0);
                        key = (lower == up) ? min(key, other) : max(key, other);
                    }
                }
                if (lane < cnt) col[beg + lane] = key;
            } else if (lane == 0) {
                for (int i = 1; i < cnt; ++i) {
                    int key = col[beg + i];
                    int j = i - 1;
                    while (j >= 0 && col[beg + j] > key) {
                        col[beg + j + 1] = col[beg + j];
                        --j;
                    }
                    col[beg + j + 1] = key;
                }
            }
        }
    }
}

// ---------------- bf16 MFMA GEMM v3: B in registers, A LDS-pipelined ----------------
// tile 64 rows x 128 cols; 4 waves, wave w owns cols [w*32, w*32+32).
// B frags (2 fn x K/32 ks) preloaded to VGPRs once -> k-loop is LDS+MFMA only.
// k-order per output identical to prior rounds -> bit-identical results.
template <int K>
__global__ __launch_bounds__(256) void k_gemm_mfma(const float* __restrict__ X,
                                                   const unsigned short* __restrict__ Wt,
                                                   unsigned short* __restrict__ Hb, int n) {
    __shared__ unsigned short As[64 * 40];
    const int tid = threadIdx.x;
    const int row0 = blockIdx.x * 64;
    const int w = tid >> 6, lane = tid & 63;
    const int lr = lane & 15, lg = lane >> 4;
    constexpr int NKS = K / 32;

    bf16x8 bfr[NKS][2];
#pragma unroll
    for (int ks = 0; ks < NKS; ++ks)
#pragma unroll
        for (int fn = 0; fn < 2; ++fn) {
            int colg = w * 32 + fn * 16 + lr;
            bfr[ks][fn] = *(const bf16x8*)&Wt[(size_t)colg * K + ks * 32 + lg * 8];
        }

    // staging slots: 64 rows x 8 float4 = 512; 2 per thread
    const int r0s = (tid * 2) >> 3, c0s = ((tid * 2) & 7) * 4;
    const int r1s = (tid * 2 + 1) >> 3, c1s = ((tid * 2 + 1) & 7) * 4;
    float4 sreg0 = make_float4(0.f, 0.f, 0.f, 0.f), sreg1 = sreg0;
    if (row0 + r0s < n) sreg0 = *(const float4*)&X[(size_t)(row0 + r0s) * K + c0s];
    if (row0 + r1s < n) sreg1 = *(const float4*)&X[(size_t)(row0 + r1s) * K + c1s];

    f32x4 acc[4][2] = {};
#pragma unroll
    for (int ks = 0; ks < NKS; ++ks) {
        __syncthreads();
        *(ushort4*)&As[r0s * 40 + c0s] =
            make_ushort4(f2b(sreg0.x), f2b(sreg0.y), f2b(sreg0.z), f2b(sreg0.w));
        *(ushort4*)&As[r1s * 40 + c1s] =
            make_ushort4(f2b(sreg1.x), f2b(sreg1.y), f2b(sreg1.z), f2b(sreg1.w));
        __syncthreads();
        if (ks + 1 < NKS) {
            sreg0 = make_float4(0.f, 0.f, 0.f, 0.f); sreg1 = sreg0;
            if (row0 + r0s < n)
                sreg0 = *(const float4*)&X[(size_t)(row0 + r0s) * K + (ks + 1) * 32 + c0s];
            if (row0 + r1s < n)
                sreg1 = *(const float4*)&X[(size_t)(row0 + r1s) * K + (ks + 1) * 32 + c1s];
        }
#pragma unroll
        for (int fm = 0; fm < 4; ++fm) {
            bf16x8 afr = *(const bf16x8*)&As[(fm * 16 + lr) * 40 + lg * 8];
#pragma unroll
            for (int fn = 0; fn < 2; ++fn)
                acc[fm][fn] = __builtin_amdgcn_mfma_f32_16x16x32_bf16(
                    afr, bfr[ks][fn], acc[fm][fn], 0, 0, 0);
        }
    }
#pragma unroll
    for (int fm = 0; fm < 4; ++fm) {
#pragma unroll
        for (int r = 0; r < 4; ++r) {
            int gr = row0 + fm * 16 + lg * 4 + r;
            if (gr < n) {
#pragma unroll
                for (int fn = 0; fn < 2; ++fn)
                    Hb[(size_t)gr * 128 + w * 32 + fn * 16 + lr] = f2b(acc[fm][fn][r]);
            }
        }
    }
}

// ---------------- fused CSR aggregation: double-buffered gather quads ----------------
__global__ __launch_bounds__(256) void k_agg_csr(const unsigned short* __restrict__ h,
                                                 const int* __restrict__ rowptr,
                                                 const int* __restrict__ counts,
                                                 const int* __restrict__ col,
                                                 const float* __restrict__ dinv,
                                                 const float* __restrict__ b,
                                                 float* __restrict__ out) {
    int t = blockIdx.x * 256 + threadIdx.x;
    int v = t >> 5;
    int lane = t & 31;
    if (v >= N_NODES) return;
    float dv = dinv[v];
    ushort4 hv = *(const ushort4*)&h[(size_t)v * HID + lane * 4];
    float sl = dv * dv;
    f32x4 a0 = {b2f(hv.x) * sl, b2f(hv.y) * sl, b2f(hv.z) * sl, b2f(hv.w) * sl};
    f32x4 a1 = {0.f, 0.f, 0.f, 0.f}, a2 = a1, a3 = a1;
    int beg = rowptr[v];
    int cnt = counts[v];
    for (int j0 = 0; j0 < cnt; j0 += 32) {
        int m = cnt - j0; if (m > 32) m = 32;
        int sj = 0; float wj = 0.f;                 // lanes >= m: w=0 -> exact no-op FMA
        if (lane < m) {
            sj = col[beg + j0 + lane];              // coalesced
            wj = dinv[sj] * dv;                     // 32 parallel random 4B gathers
        }
        int M = (m + 3) & ~3;                       // quad-padded
        float w0 = __shfl(wj, 0, 32), w1 = __shfl(wj, 1, 32);
        float w2 = __shfl(wj, 2, 32), w3 = __shfl(wj, 3, 32);
        int s0 = __shfl(sj, 0, 32), s1 = __shfl(sj, 1, 32);
        int s2 = __shfl(sj, 2, 32), s3 = __shfl(sj, 3, 32);
        ushort4 q0 = *(const ushort4*)&h[(size_t)s0 * HID + lane * 4];
        ushort4 q1 = *(const ushort4*)&h[(size_t)s1 * HID + lane * 4];
        ushort4 q2 = *(const ushort4*)&h[(size_t)s2 * HID + lane * 4];
        ushort4 q3 = *(const ushort4*)&h[(size_t)s3 * HID + lane * 4];
        for (int jj = 0; jj < M; jj += 4) {
            ushort4 n0 = q0, n1 = q1, n2 = q2, n3 = q3;
            float nw0 = 0.f, nw1 = 0.f, nw2 = 0.f, nw3 = 0.f;
            if (jj + 4 < M) {                       // prefetch next quad
                int t0 = __shfl(sj, jj + 4, 32), t1 = __shfl(sj, jj + 5, 32);
                int t2 = __shfl(sj, jj + 6, 32), t3 = __shfl(sj, jj + 7, 32);
                nw0 = __shfl(wj, jj + 4, 32); nw1 = __shfl(wj, jj + 5, 32);
                nw2 = __shfl(wj, jj + 6, 32); nw3 = __shfl(wj, jj + 7, 32);
                n0 = *(const ushort4*)&h[(size_t)t0 * HID + lane * 4];
                n1 = *(const ushort4*)&h[(size_t)t1 * HID + lane * 4];
                n2 = *(const ushort4*)&h[(size_t)t2 * HID + lane * 4];
                n3 = *(const ushort4*)&h[(size_t)t3 * HID + lane * 4];
            }
            a0[0] = fmaf(b2f(q0.x), w0, a0[0]); a0[1] = fmaf(b2f(q0.y), w0, a0[1]);
            a0[2] = fmaf(b2f(q0.z), w0, a0[2]); a0[3] = fmaf(b2f(q0.w), w0, a0[3]);
            a1[0] = fmaf(b2f(q1.x), w1, a1[0]); a1[1] = fmaf(b2f(q1.y), w1, a1[1]);
            a1[2] = fmaf(b2f(q1.z), w1, a1[2]); a1[3] = fmaf(b2f(q1.w), w1, a1[3]);
            a2[0] = fmaf(b2f(q2.x), w2, a2[0]); a2[1] = fmaf(b2f(q2.y), w2, a2[1]);
            a2[2] = fmaf(b2f(q2.z), w2, a2[2]); a2[3] = fmaf(b2f(q2.w), w2, a2[3]);
            a3[0] = fmaf(b2f(q3.x), w3, a3[0]); a3[1] = fmaf(b2f(q3.y), w3, a3[1]);
            a3[2] = fmaf(b2f(q3.z), w3, a3[2]); a3[3] = fmaf(b2f(q3.w), w3, a3[3]);
            q0 = n0; q1 = n1; q2 = n2; q3 = n3;
            w0 = nw0; w1 = nw1; w2 = nw2; w3 = nw3;
        }
    }
    float4 bv = *(const float4*)&b[lane * 4];
    float4 r;
    r.x = fmaxf((a0[0] + a1[0]) + (a2[0] + a3[0]) + bv.x, 0.f);
    r.y = fmaxf((a0[1] + a1[1]) + (a2[1] + a3[1]) + bv.y, 0.f);
    r.z = fmaxf((a0[2] + a1[2]) + (a2[2] + a3[2]) + bv.z, 0.f);
    r.w = fmaxf((a0[3] + a1[3]) + (a2[3] + a3[3]) + bv.w, 0.f);
    *(float4*)&out[(size_t)v * HID + lane * 4] = r;
}

// ---------------- final readout ----------------
__global__ void k_final(const float* __restrict__ h, const int* __restrict__ mask,
                        const float* __restrict__ Wr, const float* __restrict__ br,
                        float* __restrict__ out) {
    int t = blockIdx.x;
    int lane = threadIdx.x;
    int node = mask[t];
    float2 hv = *(const float2*)&h[(size_t)node * HID + lane * 2];
#pragma unroll
    for (int j = 0; j < OUTD; ++j) {
        float p = hv.x * Wr[(lane * 2) * OUTD + j] + hv.y * Wr[(lane * 2 + 1) * OUTD + j];
#pragma unroll
        for (int off = 32; off > 0; off >>= 1) p += __shfl_down(p, off);
        if (lane == 0) out[t * OUTD + j] = p + br[j];
    }
}

extern "C" void kernel_launch(void* const* d_in, const int* in_sizes, int n_in,
                              void* d_out, int out_size, void* d_ws, size_t ws_size,
                              hipStream_t stream) {
    const float* x  = (const float*)d_in[0];
    const int*   ei = (const int*)d_in[1];
    const int*   tm = (const int*)d_in[2];
    const float* W1 = (const float*)d_in[3];
    const float* b1 = (const float*)d_in[4];
    const float* W2 = (const float*)d_in[5];
    const float* b2 = (const float*)d_in[6];
    const float* Wr = (const float*)d_in[7];
    const float* br = (const float*)d_in[8];
    float* out = (float*)d_out;

    const int* e_src = ei;
    const int* e_dst = ei + N_EDGES;

    // workspace layout — all ranges disjoint:
    //   dinv     [0x000000)  counts [0x040000)  rowptr [0x080000)  cursor [0x0C0000)
    //   partials [0x0F8000)  bar    [0x0F8400)  col    [0x100000, 0x40D400)
    //   Wt1 [0x410000)  Wt2 [0x430000)  bufA(bf16) [0x500000)  bufB(f32) [0x1200000)
    char* ws = (char*)d_ws;
    float*          dinv     = (float*)(ws + 0x000000);
    int*            counts   = (int*)  (ws + 0x040000);
    int*            rowptr   = (int*)  (ws + 0x080000);
    int*            cursor   = (int*)  (ws + 0x0C0000);
    int*            partials = (int*)  (ws + 0x0F8000);
    int*            bar      = (int*)  (ws + 0x0F8400);
    int*            col      = (int*)  (ws + 0x100000);
    unsigned short* Wt1      = (unsigned short*)(ws + 0x410000);
    unsigned short* Wt2      = (unsigned short*)(ws + 0x430000);
    unsigned short* bufA     = (unsigned short*)(ws + 0x500000);
    float*          bufB     = (float*)(ws + 0x1200000);

    const int NB_AGG = (N_NODES * 32 + 255) / 256;
    const int NB_MF  = (N_NODES + 63) / 64;

    // ---- CSR build: 2 launches total ----
    k_zero0<<<SCAN_NB, 256, 0, stream>>>(counts, bar);
    k_csr<<<GB, 256, 0, stream>>>(e_src, e_dst, counts, partials, rowptr, cursor, dinv,
                                  col, W1, Wt1, W2, Wt2, bar, bar + 1);

    // ---- layer 1 ----
    k_gemm_mfma<EMBED><<<NB_MF, 256, 0, stream>>>(x, Wt1, bufA, N_NODES);
    k_agg_csr<<<NB_AGG, 256, 0, stream>>>(bufA, rowptr, counts, col, dinv, b1, bufB);

    // ---- layer 2 ----
    k_gemm_mfma<HID><<<NB_MF, 256, 0, stream>>>(bufB, Wt2, bufA, N_NODES);
    k_agg_csr<<<NB_AGG, 256, 0, stream>>>(bufA, rowptr, counts, col, dinv, b2, bufB);

    // ---- readout ----
    k_final<<<N_TGT, 64, 0, stream>>>(bufB, tm, Wr, br, out);
}

// Round 13
// 217.239 us; speedup vs baseline: 2.1550x; 2.1550x over previous
//
#include <hip/hip_runtime.h>
#include <math.h>

#define N_NODES 50000
#define N_EDGES 800000
#define EMBED 256
#define HID 128
#define OUTD 12
#define N_TGT 4096

#define SCAN_NB 196   // ceil(50000/256)
#define NPART 8       // XCD count; blockIdx&7 ~ XCD id (round-robin dispatch)
#define NODES_PER_PART 6250  // 50000/8

typedef short bf16x8 __attribute__((ext_vector_type(8)));
typedef float f32x4 __attribute__((ext_vector_type(4)));

// f32 -> bf16 round-to-nearest-even (bit-exact, deterministic)
__device__ __forceinline__ unsigned short f2b(float f) {
    union { float f; unsigned int u; } v;
    v.f = f;
    unsigned int u = v.u;
    return (unsigned short)((u + 0x7FFFu + ((u >> 16) & 1u)) >> 16);
}

__device__ __forceinline__ float b2f(unsigned short s) {
    union { unsigned int u; float f; } v;
    v.u = ((unsigned int)s) << 16;
    return v.f;
}

// ---------------- zero counts ----------------
__global__ void k_zero(int* __restrict__ p, int n) {
    int i = blockIdx.x * 256 + threadIdx.x;
    if (i < n) p[i] = 0;
}

// ---------------- CSR build (XCD-partitioned atomics, wide grid) ----------------
__global__ void k_hist(const int* __restrict__ dst, int* __restrict__ counts, int nE) {
    int g = blockIdx.x & (NPART - 1);
    int i = (blockIdx.x >> 3) * 256 + threadIdx.x;
    if (i >= nE) return;
    int d = dst[i];
    if ((unsigned)(d - g * NODES_PER_PART) < (unsigned)NODES_PER_PART)
        atomicAdd(&counts[d], 1);
}

__global__ void k_fill(const int* __restrict__ src, const int* __restrict__ dst,
                       int* __restrict__ cursor, int* __restrict__ col, int nE) {
    int g = blockIdx.x & (NPART - 1);
    int i = (blockIdx.x >> 3) * 256 + threadIdx.x;
    if (i >= nE) return;
    int d = dst[i];
    if ((unsigned)(d - g * NODES_PER_PART) < (unsigned)NODES_PER_PART) {
        int pos = atomicAdd(&cursor[d], 1);
        col[pos] = src[i];
    }
}

__global__ __launch_bounds__(256) void k_scan_part(const int* __restrict__ counts,
                                                   int* __restrict__ partials) {
    __shared__ int ws[4];
    int i = blockIdx.x * 256 + threadIdx.x;
    int v = (i < N_NODES) ? counts[i] : 0;
#pragma unroll
    for (int off = 32; off > 0; off >>= 1) v += __shfl_down(v, off);
    int wid = threadIdx.x >> 6;
    if ((threadIdx.x & 63) == 0) ws[wid] = v;
    __syncthreads();
    if (threadIdx.x == 0) partials[blockIdx.x] = ws[0] + ws[1] + ws[2] + ws[3];
}

__global__ __launch_bounds__(256) void k_scan_top(int* __restrict__ partials) {
    __shared__ int s[256];
    int tid = threadIdx.x;
    int v = (tid < SCAN_NB) ? partials[tid] : 0;
    s[tid] = v;
    __syncthreads();
#pragma unroll
    for (int off = 1; off < 256; off <<= 1) {
        int t = (tid >= off) ? s[tid - off] : 0;
        __syncthreads();
        s[tid] += t;
        __syncthreads();
    }
    if (tid < SCAN_NB) partials[tid] = s[tid] - v;  // exclusive
}

__global__ __launch_bounds__(256) void k_scan_final(const int* __restrict__ counts,
                                                    const int* __restrict__ partials,
                                                    int* __restrict__ rowptr,
                                                    int* __restrict__ cursor,
                                                    float* __restrict__ dinv) {
    __shared__ int s[256];
    int tid = threadIdx.x;
    int i = blockIdx.x * 256 + tid;
    int c = (i < N_NODES) ? counts[i] : 0;
    s[tid] = c;
    __syncthreads();
#pragma unroll
    for (int off = 1; off < 256; off <<= 1) {
        int t = (tid >= off) ? s[tid - off] : 0;
        __syncthreads();
        s[tid] += t;
        __syncthreads();
    }
    if (i < N_NODES) {
        int rp = partials[blockIdx.x] + s[tid] - c;  // exclusive
        rowptr[i] = rp;
        cursor[i] = rp;
        dinv[i] = rsqrtf(1.0f + (float)c);
    }
}

// one WAVE per row, 64-lane bitonic sort in registers (determinism canonicalizer)
__global__ __launch_bounds__(256) void k_sort_rows(const int* __restrict__ rowptr,
                                                   const int* __restrict__ counts,
                                                   int* __restrict__ col) {
    int wid = threadIdx.x >> 6;
    int lane = threadIdx.x & 63;
    int v = blockIdx.x * 4 + wid;
    if (v >= N_NODES) return;
    int beg = rowptr[v], cnt = counts[v];
    if (cnt <= 1) return;
    if (cnt <= 64) {
        int key = (lane < cnt) ? col[beg + lane] : 0x7FFFFFFF;
#pragma unroll
        for (int k = 2; k <= 64; k <<= 1) {
#pragma unroll
            for (int j = k >> 1; j > 0; j >>= 1) {
                int other = __shfl_xor(key, j);
                bool up = ((lane & k) == 0);
                bool lower = ((lane & j) == 0);
                key = (lower == up) ? min(key, other) : max(key, other);
            }
        }
        if (lane < cnt) col[beg + lane] = key;
    } else if (lane == 0) {
        for (int i = 1; i < cnt; ++i) {
            int key = col[beg + i];
            int j = i - 1;
            while (j >= 0 && col[beg + j] > key) {
                col[beg + j + 1] = col[beg + j];
                --j;
            }
            col[beg + j + 1] = key;
        }
    }
}

// ---------------- W[k][n] f32 -> Wt[n][k] bf16 ----------------
__global__ void k_convW(const float* __restrict__ W, unsigned short* __restrict__ Wt, int K) {
    int i = blockIdx.x * 256 + threadIdx.x;
    if (i >= 128 * K) return;
    int n = i / K;
    int k = i - n * K;
    Wt[(size_t)n * K + k] = f2b(W[(size_t)k * 128 + n]);
}

// ---------------- bf16 MFMA GEMM v3: B in registers, A LDS-pipelined ----------------
// tile 64 rows x 128 cols; 4 waves, wave w owns cols [w*32, w*32+32).
// B frags (2 fn x K/32 ks) preloaded to VGPRs once -> k-loop is LDS+MFMA only.
template <int K>
__global__ __launch_bounds__(256) void k_gemm_mfma(const float* __restrict__ X,
                                                   const unsigned short* __restrict__ Wt,
                                                   unsigned short* __restrict__ Hb, int n) {
    __shared__ unsigned short As[64 * 40];
    const int tid = threadIdx.x;
    const int row0 = blockIdx.x * 64;
    const int w = tid >> 6, lane = tid & 63;
    const int lr = lane & 15, lg = lane >> 4;
    constexpr int NKS = K / 32;

    bf16x8 bfr[NKS][2];
#pragma unroll
    for (int ks = 0; ks < NKS; ++ks)
#pragma unroll
        for (int fn = 0; fn < 2; ++fn) {
            int colg = w * 32 + fn * 16 + lr;
            bfr[ks][fn] = *(const bf16x8*)&Wt[(size_t)colg * K + ks * 32 + lg * 8];
        }

    // staging slots: 64 rows x 8 float4 = 512; 2 per thread
    const int r0s = (tid * 2) >> 3, c0s = ((tid * 2) & 7) * 4;
    const int r1s = (tid * 2 + 1) >> 3, c1s = ((tid * 2 + 1) & 7) * 4;
    float4 sreg0 = make_float4(0.f, 0.f, 0.f, 0.f), sreg1 = sreg0;
    if (row0 + r0s < n) sreg0 = *(const float4*)&X[(size_t)(row0 + r0s) * K + c0s];
    if (row0 + r1s < n) sreg1 = *(const float4*)&X[(size_t)(row0 + r1s) * K + c1s];

    f32x4 acc[4][2] = {};
#pragma unroll
    for (int ks = 0; ks < NKS; ++ks) {
        __syncthreads();
        *(ushort4*)&As[r0s * 40 + c0s] =
            make_ushort4(f2b(sreg0.x), f2b(sreg0.y), f2b(sreg0.z), f2b(sreg0.w));
        *(ushort4*)&As[r1s * 40 + c1s] =
            make_ushort4(f2b(sreg1.x), f2b(sreg1.y), f2b(sreg1.z), f2b(sreg1.w));
        __syncthreads();
        if (ks + 1 < NKS) {
            sreg0 = make_float4(0.f, 0.f, 0.f, 0.f); sreg1 = sreg0;
            if (row0 + r0s < n)
                sreg0 = *(const float4*)&X[(size_t)(row0 + r0s) * K + (ks + 1) * 32 + c0s];
            if (row0 + r1s < n)
                sreg1 = *(const float4*)&X[(size_t)(row0 + r1s) * K + (ks + 1) * 32 + c1s];
        }
#pragma unroll
        for (int fm = 0; fm < 4; ++fm) {
            bf16x8 afr = *(const bf16x8*)&As[(fm * 16 + lr) * 40 + lg * 8];
#pragma unroll
            for (int fn = 0; fn < 2; ++fn)
                acc[fm][fn] = __builtin_amdgcn_mfma_f32_16x16x32_bf16(
                    afr, bfr[ks][fn], acc[fm][fn], 0, 0, 0);
        }
    }
#pragma unroll
    for (int fm = 0; fm < 4; ++fm) {
#pragma unroll
        for (int r = 0; r < 4; ++r) {
            int gr = row0 + fm * 16 + lg * 4 + r;
            if (gr < n) {
#pragma unroll
                for (int fn = 0; fn < 2; ++fn)
                    Hb[(size_t)gr * 128 + w * 32 + fn * 16 + lr] = f2b(acc[fm][fn][r]);
            }
        }
    }
}

// ---------------- fused CSR aggregation: double-buffered gather quads ----------------
__global__ __launch_bounds__(256) void k_agg_csr(const unsigned short* __restrict__ h,
                                                 const int* __restrict__ rowptr,
                                                 const int* __restrict__ counts,
                                                 const int* __restrict__ col,
                                                 const float* __restrict__ dinv,
                                                 const float* __restrict__ b,
                                                 float* __restrict__ out) {
    int t = blockIdx.x * 256 + threadIdx.x;
    int v = t >> 5;
    int lane = t & 31;
    if (v >= N_NODES) return;
    float dv = dinv[v];
    ushort4 hv = *(const ushort4*)&h[(size_t)v * HID + lane * 4];
    float sl = dv * dv;
    f32x4 a0 = {b2f(hv.x) * sl, b2f(hv.y) * sl, b2f(hv.z) * sl, b2f(hv.w) * sl};
    f32x4 a1 = {0.f, 0.f, 0.f, 0.f}, a2 = a1, a3 = a1;
    int beg = rowptr[v];
    int cnt = counts[v];
    for (int j0 = 0; j0 < cnt; j0 += 32) {
        int m = cnt - j0; if (m > 32) m = 32;
        int sj = 0; float wj = 0.f;                 // lanes >= m: w=0 -> exact no-op FMA
        if (lane < m) {
            sj = col[beg + j0 + lane];              // coalesced
            wj = dinv[sj] * dv;                     // 32 parallel random 4B gathers
        }
        int M = (m + 3) & ~3;                       // quad-padded
        float w0 = __shfl(wj, 0, 32), w1 = __shfl(wj, 1, 32);
        float w2 = __shfl(wj, 2, 32), w3 = __shfl(wj, 3, 32);
        int s0 = __shfl(sj, 0, 32), s1 = __shfl(sj, 1, 32);
        int s2 = __shfl(sj, 2, 32), s3 = __shfl(sj, 3, 32);
        ushort4 q0 = *(const ushort4*)&h[(size_t)s0 * HID + lane * 4];
        ushort4 q1 = *(const ushort4*)&h[(size_t)s1 * HID + lane * 4];
        ushort4 q2 = *(const ushort4*)&h[(size_t)s2 * HID + lane * 4];
        ushort4 q3 = *(const ushort4*)&h[(size_t)s3 * HID + lane * 4];
        for (int jj = 0; jj < M; jj += 4) {
            ushort4 n0 = q0, n1 = q1, n2 = q2, n3 = q3;
            float nw0 = 0.f, nw1 = 0.f, nw2 = 0.f, nw3 = 0.f;
            if (jj + 4 < M) {                       // prefetch next quad
                int t0 = __shfl(sj, jj + 4, 32), t1 = __shfl(sj, jj + 5, 32);
                int t2 = __shfl(sj, jj + 6, 32), t3 = __shfl(sj, jj + 7, 32);
                nw0 = __shfl(wj, jj + 4, 32); nw1 = __shfl(wj, jj + 5, 32);
                nw2 = __shfl(wj, jj + 6, 32); nw3 = __shfl(wj, jj + 7, 32);
                n0 = *(const ushort4*)&h[(size_t)t0 * HID + lane * 4];
                n1 = *(const ushort4*)&h[(size_t)t1 * HID + lane * 4];
                n2 = *(const ushort4*)&h[(size_t)t2 * HID + lane * 4];
                n3 = *(const ushort4*)&h[(size_t)t3 * HID + lane * 4];
            }
            a0[0] = fmaf(b2f(q0.x), w0, a0[0]); a0[1] = fmaf(b2f(q0.y), w0, a0[1]);
            a0[2] = fmaf(b2f(q0.z), w0, a0[2]); a0[3] = fmaf(b2f(q0.w), w0, a0[3]);
            a1[0] = fmaf(b2f(q1.x), w1, a1[0]); a1[1] = fmaf(b2f(q1.y), w1, a1[1]);
            a1[2] = fmaf(b2f(q1.z), w1, a1[2]); a1[3] = fmaf(b2f(q1.w), w1, a1[3]);
            a2[0] = fmaf(b2f(q2.x), w2, a2[0]); a2[1] = fmaf(b2f(q2.y), w2, a2[1]);
            a2[2] = fmaf(b2f(q2.z), w2, a2[2]); a2[3] = fmaf(b2f(q2.w), w2, a2[3]);
            a3[0] = fmaf(b2f(q3.x), w3, a3[0]); a3[1] = fmaf(b2f(q3.y), w3, a3[1]);
            a3[2] = fmaf(b2f(q3.z), w3, a3[2]); a3[3] = fmaf(b2f(q3.w), w3, a3[3]);
            q0 = n0; q1 = n1; q2 = n2; q3 = n3;
            w0 = nw0; w1 = nw1; w2 = nw2; w3 = nw3;
        }
    }
    float4 bv = *(const float4*)&b[lane * 4];
    float4 r;
    r.x = fmaxf((a0[0] + a1[0]) + (a2[0] + a3[0]) + bv.x, 0.f);
    r.y = fmaxf((a0[1] + a1[1]) + (a2[1] + a3[1]) + bv.y, 0.f);
    r.z = fmaxf((a0[2] + a1[2]) + (a2[2] + a3[2]) + bv.z, 0.f);
    r.w = fmaxf((a0[3] + a1[3]) + (a2[3] + a3[3]) + bv.w, 0.f);
    *(float4*)&out[(size_t)v * HID + lane * 4] = r;
}

// ---------------- final readout ----------------
__global__ void k_final(const float* __restrict__ h, const int* __restrict__ mask,
                        const float* __restrict__ Wr, const float* __restrict__ br,
                        float* __restrict__ out) {
    int t = blockIdx.x;
    int lane = threadIdx.x;
    int node = mask[t];
    float2 hv = *(const float2*)&h[(size_t)node * HID + lane * 2];
#pragma unroll
    for (int j = 0; j < OUTD; ++j) {
        float p = hv.x * Wr[(lane * 2) * OUTD + j] + hv.y * Wr[(lane * 2 + 1) * OUTD + j];
#pragma unroll
        for (int off = 32; off > 0; off >>= 1) p += __shfl_down(p, off);
        if (lane == 0) out[t * OUTD + j] = p + br[j];
    }
}

extern "C" void kernel_launch(void* const* d_in, const int* in_sizes, int n_in,
                              void* d_out, int out_size, void* d_ws, size_t ws_size,
                              hipStream_t stream) {
    const float* x  = (const float*)d_in[0];
    const int*   ei = (const int*)d_in[1];
    const int*   tm = (const int*)d_in[2];
    const float* W1 = (const float*)d_in[3];
    const float* b1 = (const float*)d_in[4];
    const float* W2 = (const float*)d_in[5];
    const float* b2 = (const float*)d_in[6];
    const float* Wr = (const float*)d_in[7];
    const float* br = (const float*)d_in[8];
    float* out = (float*)d_out;

    const int* e_src = ei;
    const int* e_dst = ei + N_EDGES;

    // workspace layout — all ranges disjoint (see R4 postmortem):
    char* ws = (char*)d_ws;
    float*          dinv     = (float*)(ws + 0x000000);
    int*            counts   = (int*)  (ws + 0x040000);
    int*            rowptr   = (int*)  (ws + 0x080000);
    int*            cursor   = (int*)  (ws + 0x0C0000);
    int*            partials = (int*)  (ws + 0x0F8000);
    int*            col      = (int*)  (ws + 0x100000);
    unsigned short* Wt1      = (unsigned short*)(ws + 0x410000);
    unsigned short* Wt2      = (unsigned short*)(ws + 0x430000);
    unsigned short* bufA     = (unsigned short*)(ws + 0x500000);
    float*          bufB     = (float*)(ws + 0x1200000);

    const int NB_E    = (N_EDGES + 255) / 256;
    const int NB_EP   = NB_E * NPART;          // partitioned edge kernels (wide grid)
    const int NB_AGG  = (N_NODES * 32 + 255) / 256;
    const int NB_MF   = (N_NODES + 63) / 64;   // 64-row tiles
    const int NB_SORT = (N_NODES + 3) / 4;

    // ---- CSR build (by dst, XCD-partitioned, wide grids) ----
    k_zero<<<SCAN_NB, 256, 0, stream>>>(counts, N_NODES);
    k_hist<<<NB_EP, 256, 0, stream>>>(e_dst, counts, N_EDGES);
    k_scan_part<<<SCAN_NB, 256, 0, stream>>>(counts, partials);
    k_scan_top<<<1, 256, 0, stream>>>(partials);
    k_scan_final<<<SCAN_NB, 256, 0, stream>>>(counts, partials, rowptr, cursor, dinv);
    k_fill<<<NB_EP, 256, 0, stream>>>(e_src, e_dst, cursor, col, N_EDGES);
    k_sort_rows<<<NB_SORT, 256, 0, stream>>>(rowptr, counts, col);
    k_convW<<<(128 * EMBED + 255) / 256, 256, 0, stream>>>(W1, Wt1, EMBED);
    k_convW<<<(128 * HID + 255) / 256, 256, 0, stream>>>(W2, Wt2, HID);

    // ---- layer 1 ----
    k_gemm_mfma<EMBED><<<NB_MF, 256, 0, stream>>>(x, Wt1, bufA, N_NODES);
    k_agg_csr<<<NB_AGG, 256, 0, stream>>>(bufA, rowptr, counts, col, dinv, b1, bufB);

    // ---- layer 2 ----
    k_gemm_mfma<HID><<<NB_MF, 256, 0, stream>>>(bufB, Wt2, bufA, N_NODES);
    k_agg_csr<<<NB_AGG, 256, 0, stream>>>(bufA, rowptr, counts, col, dinv, b2, bufB);

    // ---- readout ----
    k_final<<<N_TGT, 64, 0, stream>>>(bufB, tm, Wr, br, out);
}

// Round 14
// 213.502 us; speedup vs baseline: 2.1927x; 1.0175x over previous
//
#include <hip/hip_runtime.h>
#include <math.h>

#define N_NODES 50000
#define N_EDGES 800000
#define EMBED 256
#define HID 128
#define OUTD 12
#define N_TGT 4096

#define SCAN_NB 196   // ceil(50000/256)
#define NPART 8       // XCD count; blockIdx&7 ~ XCD id (round-robin dispatch)
#define NODES_PER_PART 6250  // 50000/8

typedef short bf16x8 __attribute__((ext_vector_type(8)));
typedef float f32x4 __attribute__((ext_vector_type(4)));

// f32 -> bf16 round-to-nearest-even (bit-exact, deterministic)
__device__ __forceinline__ unsigned short f2b(float f) {
    union { float f; unsigned int u; } v;
    v.f = f;
    unsigned int u = v.u;
    return (unsigned short)((u + 0x7FFFu + ((u >> 16) & 1u)) >> 16);
}

__device__ __forceinline__ float b2f(unsigned short s) {
    union { unsigned int u; float f; } v;
    v.u = ((unsigned int)s) << 16;
    return v.f;
}

// ---------------- prelude: zero counts + convert both weight matrices ----------------
__global__ __launch_bounds__(256) void k_prelude(int* __restrict__ counts,
                                                 const float* __restrict__ W1,
                                                 unsigned short* __restrict__ Wt1,
                                                 const float* __restrict__ W2,
                                                 unsigned short* __restrict__ Wt2) {
    int i = blockIdx.x * 256 + threadIdx.x;     // grid 196*256 = 50176
    if (i < N_NODES) counts[i] = 0;
    if (i < 32768) {                            // Wt1: 128 x 256
        int nn = i >> 8, k = i & 255;
        Wt1[nn * 256 + k] = f2b(W1[(size_t)k * 128 + nn]);
    } else if (i < 49152) {                     // Wt2: 128 x 128
        int j = i - 32768;
        int nn = j >> 7, k = j & 127;
        Wt2[nn * 128 + k] = f2b(W2[(size_t)k * 128 + nn]);
    }
}

// ---------------- CSR build (XCD-partitioned atomics, int4-vectorized) ----------------
__global__ void k_hist(const int* __restrict__ dst, int* __restrict__ counts, int nE4) {
    int g = blockIdx.x & (NPART - 1);
    int i = (blockIdx.x >> 3) * 256 + threadIdx.x;   // int4 index
    if (i >= nE4) return;
    int4 d4 = *(const int4*)&dst[i * 4];
#pragma unroll
    for (int q = 0; q < 4; ++q) {
        int d = (&d4.x)[q];
        if ((unsigned)(d - g * NODES_PER_PART) < (unsigned)NODES_PER_PART)
            atomicAdd(&counts[d], 1);
    }
}

__global__ void k_fill(const int* __restrict__ src, const int* __restrict__ dst,
                       int* __restrict__ cursor, int* __restrict__ col, int nE4) {
    int g = blockIdx.x & (NPART - 1);
    int i = (blockIdx.x >> 3) * 256 + threadIdx.x;
    if (i >= nE4) return;
    int4 d4 = *(const int4*)&dst[i * 4];
    int4 s4 = *(const int4*)&src[i * 4];
#pragma unroll
    for (int q = 0; q < 4; ++q) {
        int d = (&d4.x)[q];
        if ((unsigned)(d - g * NODES_PER_PART) < (unsigned)NODES_PER_PART) {
            int pos = atomicAdd(&cursor[d], 1);
            col[pos] = (&s4.x)[q];
        }
    }
}

__global__ __launch_bounds__(256) void k_scan_part(const int* __restrict__ counts,
                                                   int* __restrict__ partials) {
    __shared__ int ws[4];
    int i = blockIdx.x * 256 + threadIdx.x;
    int v = (i < N_NODES) ? counts[i] : 0;
#pragma unroll
    for (int off = 32; off > 0; off >>= 1) v += __shfl_down(v, off);
    int wid = threadIdx.x >> 6;
    if ((threadIdx.x & 63) == 0) ws[wid] = v;
    __syncthreads();
    if (threadIdx.x == 0) partials[blockIdx.x] = ws[0] + ws[1] + ws[2] + ws[3];
}

__global__ __launch_bounds__(256) void k_scan_top(int* __restrict__ partials) {
    __shared__ int s[256];
    int tid = threadIdx.x;
    int v = (tid < SCAN_NB) ? partials[tid] : 0;
    s[tid] = v;
    __syncthreads();
#pragma unroll
    for (int off = 1; off < 256; off <<= 1) {
        int t = (tid >= off) ? s[tid - off] : 0;
        __syncthreads();
        s[tid] += t;
        __syncthreads();
    }
    if (tid < SCAN_NB) partials[tid] = s[tid] - v;  // exclusive
}

__global__ __launch_bounds__(256) void k_scan_final(const int* __restrict__ counts,
                                                    const int* __restrict__ partials,
                                                    int* __restrict__ rowptr,
                                                    int* __restrict__ cursor,
                                                    float* __restrict__ dinv) {
    __shared__ int s[256];
    int tid = threadIdx.x;
    int i = blockIdx.x * 256 + tid;
    int c = (i < N_NODES) ? counts[i] : 0;
    s[tid] = c;
    __syncthreads();
#pragma unroll
    for (int off = 1; off < 256; off <<= 1) {
        int t = (tid >= off) ? s[tid - off] : 0;
        __syncthreads();
        s[tid] += t;
        __syncthreads();
    }
    if (i < N_NODES) {
        int rp = partials[blockIdx.x] + s[tid] - c;  // exclusive
        rowptr[i] = rp;
        cursor[i] = rp;
        dinv[i] = rsqrtf(1.0f + (float)c);
    }
}

// one WAVE per row, 64-lane bitonic sort in registers (determinism canonicalizer)
__global__ __launch_bounds__(256) void k_sort_rows(const int* __restrict__ rowptr,
                                                   const int* __restrict__ counts,
                                                   int* __restrict__ col) {
    int wid = threadIdx.x >> 6;
    int lane = threadIdx.x & 63;
    int v = blockIdx.x * 4 + wid;
    if (v >= N_NODES) return;
    int beg = rowptr[v], cnt = counts[v];
    if (cnt <= 1) return;
    if (cnt <= 64) {
        int key = (lane < cnt) ? col[beg + lane] : 0x7FFFFFFF;
#pragma unroll
        for (int k = 2; k <= 64; k <<= 1) {
#pragma unroll
            for (int j = k >> 1; j > 0; j >>= 1) {
                int other = __shfl_xor(key, j);
                bool up = ((lane & k) == 0);
                bool lower = ((lane & j) == 0);
                key = (lower == up) ? min(key, other) : max(key, other);
            }
        }
        if (lane < cnt) col[beg + lane] = key;
    } else if (lane == 0) {
        for (int i = 1; i < cnt; ++i) {
            int key = col[beg + i];
            int j = i - 1;
            while (j >= 0 && col[beg + j] > key) {
                col[beg + j + 1] = col[beg + j];
                --j;
            }
            col[beg + j + 1] = key;
        }
    }
}

// ---------------- bf16 MFMA GEMM v3: B in registers, A LDS-pipelined ----------------
// tile 64 rows x 128 cols; 4 waves, wave w owns cols [w*32, w*32+32).
// IS_BF16: input already bf16 (stage bits directly -> bit-identical to f32 path).
template <int K, bool IS_BF16>
__global__ __launch_bounds__(256) void k_gemm_mfma(const void* __restrict__ Xv,
                                                   const unsigned short* __restrict__ Wt,
                                                   unsigned short* __restrict__ Hb, int n) {
    __shared__ unsigned short As[64 * 40];
    const int tid = threadIdx.x;
    const int row0 = blockIdx.x * 64;
    const int w = tid >> 6, lane = tid & 63;
    const int lr = lane & 15, lg = lane >> 4;
    constexpr int NKS = K / 32;

    bf16x8 bfr[NKS][2];
#pragma unroll
    for (int ks = 0; ks < NKS; ++ks)
#pragma unroll
        for (int fn = 0; fn < 2; ++fn) {
            int colg = w * 32 + fn * 16 + lr;
            bfr[ks][fn] = *(const bf16x8*)&Wt[(size_t)colg * K + ks * 32 + lg * 8];
        }

    // staging slots: 64 rows x 8 slots(4 elems); 2 per thread
    const int r0s = (tid * 2) >> 3, c0s = ((tid * 2) & 7) * 4;
    const int r1s = (tid * 2 + 1) >> 3, c1s = ((tid * 2 + 1) & 7) * 4;

    const float* Xf = (const float*)Xv;
    const unsigned short* Xb = (const unsigned short*)Xv;

    float4 f0 = make_float4(0.f, 0.f, 0.f, 0.f), f1 = f0;
    ushort4 u0 = make_ushort4(0, 0, 0, 0), u1 = u0;
    if (IS_BF16) {
        if (row0 + r0s < n) u0 = *(const ushort4*)&Xb[(size_t)(row0 + r0s) * K + c0s];
        if (row0 + r1s < n) u1 = *(const ushort4*)&Xb[(size_t)(row0 + r1s) * K + c1s];
    } else {
        if (row0 + r0s < n) f0 = *(const float4*)&Xf[(size_t)(row0 + r0s) * K + c0s];
        if (row0 + r1s < n) f1 = *(const float4*)&Xf[(size_t)(row0 + r1s) * K + c1s];
    }

    f32x4 acc[4][2] = {};
#pragma unroll
    for (int ks = 0; ks < NKS; ++ks) {
        __syncthreads();
        if (IS_BF16) {
            *(ushort4*)&As[r0s * 40 + c0s] = u0;
            *(ushort4*)&As[r1s * 40 + c1s] = u1;
        } else {
            *(ushort4*)&As[r0s * 40 + c0s] = make_ushort4(f2b(f0.x), f2b(f0.y), f2b(f0.z), f2b(f0.w));
            *(ushort4*)&As[r1s * 40 + c1s] = make_ushort4(f2b(f1.x), f2b(f1.y), f2b(f1.z), f2b(f1.w));
        }
        __syncthreads();
        if (ks + 1 < NKS) {
            int ko = (ks + 1) * 32;
            if (IS_BF16) {
                u0 = make_ushort4(0, 0, 0, 0); u1 = u0;
                if (row0 + r0s < n) u0 = *(const ushort4*)&Xb[(size_t)(row0 + r0s) * K + ko + c0s];
                if (row0 + r1s < n) u1 = *(const ushort4*)&Xb[(size_t)(row0 + r1s) * K + ko + c1s];
            } else {
                f0 = make_float4(0.f, 0.f, 0.f, 0.f); f1 = f0;
                if (row0 + r0s < n) f0 = *(const float4*)&Xf[(size_t)(row0 + r0s) * K + ko + c0s];
                if (row0 + r1s < n) f1 = *(const float4*)&Xf[(size_t)(row0 + r1s) * K + ko + c1s];
            }
        }
#pragma unroll
        for (int fm = 0; fm < 4; ++fm) {
            bf16x8 afr = *(const bf16x8*)&As[(fm * 16 + lr) * 40 + lg * 8];
#pragma unroll
            for (int fn = 0; fn < 2; ++fn)
                acc[fm][fn] = __builtin_amdgcn_mfma_f32_16x16x32_bf16(
                    afr, bfr[ks][fn], acc[fm][fn], 0, 0, 0);
        }
    }
#pragma unroll
    for (int fm = 0; fm < 4; ++fm) {
#pragma unroll
        for (int r = 0; r < 4; ++r) {
            int gr = row0 + fm * 16 + lg * 4 + r;
            if (gr < n) {
#pragma unroll
                for (int fn = 0; fn < 2; ++fn)
                    Hb[(size_t)gr * 128 + w * 32 + fn * 16 + lr] = f2b(acc[fm][fn][r]);
            }
        }
    }
}

// ---------------- fused CSR aggregation: double-buffered gather quads, bf16 out ----------------
__global__ __launch_bounds__(256) void k_agg_csr(const unsigned short* __restrict__ h,
                                                 const int* __restrict__ rowptr,
                                                 const int* __restrict__ counts,
                                                 const int* __restrict__ col,
                                                 const float* __restrict__ dinv,
                                                 const float* __restrict__ b,
                                                 unsigned short* __restrict__ out) {
    int t = blockIdx.x * 256 + threadIdx.x;
    int v = t >> 5;
    int lane = t & 31;
    if (v >= N_NODES) return;
    float dv = dinv[v];
    ushort4 hv = *(const ushort4*)&h[(size_t)v * HID + lane * 4];
    float sl = dv * dv;
    f32x4 a0 = {b2f(hv.x) * sl, b2f(hv.y) * sl, b2f(hv.z) * sl, b2f(hv.w) * sl};
    f32x4 a1 = {0.f, 0.f, 0.f, 0.f}, a2 = a1, a3 = a1;
    int beg = rowptr[v];
    int cnt = counts[v];
    for (int j0 = 0; j0 < cnt; j0 += 32) {
        int m = cnt - j0; if (m > 32) m = 32;
        int sj = 0; float wj = 0.f;                 // lanes >= m: w=0 -> exact no-op FMA
        if (lane < m) {
            sj = col[beg + j0 + lane];              // coalesced
            wj = dinv[sj] * dv;                     // 32 parallel random 4B gathers
        }
        int M = (m + 3) & ~3;                       // quad-padded
        float w0 = __shfl(wj, 0, 32), w1 = __shfl(wj, 1, 32);
        float w2 = __shfl(wj, 2, 32), w3 = __shfl(wj, 3, 32);
        int s0 = __shfl(sj, 0, 32), s1 = __shfl(sj, 1, 32);
        int s2 = __shfl(sj, 2, 32), s3 = __shfl(sj, 3, 32);
        ushort4 q0 = *(const ushort4*)&h[(size_t)s0 * HID + lane * 4];
        ushort4 q1 = *(const ushort4*)&h[(size_t)s1 * HID + lane * 4];
        ushort4 q2 = *(const ushort4*)&h[(size_t)s2 * HID + lane * 4];
        ushort4 q3 = *(const ushort4*)&h[(size_t)s3 * HID + lane * 4];
        for (int jj = 0; jj < M; jj += 4) {
            ushort4 n0 = q0, n1 = q1, n2 = q2, n3 = q3;
            float nw0 = 0.f, nw1 = 0.f, nw2 = 0.f, nw3 = 0.f;
            if (jj + 4 < M) {                       // prefetch next quad
                int t0 = __shfl(sj, jj + 4, 32), t1 = __shfl(sj, jj + 5, 32);
                int t2 = __shfl(sj, jj + 6, 32), t3 = __shfl(sj, jj + 7, 32);
                nw0 = __shfl(wj, jj + 4, 32); nw1 = __shfl(wj, jj + 5, 32);
                nw2 = __shfl(wj, jj + 6, 32); nw3 = __shfl(wj, jj + 7, 32);
                n0 = *(const ushort4*)&h[(size_t)t0 * HID + lane * 4];
                n1 = *(const ushort4*)&h[(size_t)t1 * HID + lane * 4];
                n2 = *(const ushort4*)&h[(size_t)t2 * HID + lane * 4];
                n3 = *(const ushort4*)&h[(size_t)t3 * HID + lane * 4];
            }
            a0[0] = fmaf(b2f(q0.x), w0, a0[0]); a0[1] = fmaf(b2f(q0.y), w0, a0[1]);
            a0[2] = fmaf(b2f(q0.z), w0, a0[2]); a0[3] = fmaf(b2f(q0.w), w0, a0[3]);
            a1[0] = fmaf(b2f(q1.x), w1, a1[0]); a1[1] = fmaf(b2f(q1.y), w1, a1[1]);
            a1[2] = fmaf(b2f(q1.z), w1, a1[2]); a1[3] = fmaf(b2f(q1.w), w1, a1[3]);
            a2[0] = fmaf(b2f(q2.x), w2, a2[0]); a2[1] = fmaf(b2f(q2.y), w2, a2[1]);
            a2[2] = fmaf(b2f(q2.z), w2, a2[2]); a2[3] = fmaf(b2f(q2.w), w2, a2[3]);
            a3[0] = fmaf(b2f(q3.x), w3, a3[0]); a3[1] = fmaf(b2f(q3.y), w3, a3[1]);
            a3[2] = fmaf(b2f(q3.z), w3, a3[2]); a3[3] = fmaf(b2f(q3.w), w3, a3[3]);
            q0 = n0; q1 = n1; q2 = n2; q3 = n3;
            w0 = nw0; w1 = nw1; w2 = nw2; w3 = nw3;
        }
    }
    float4 bv = *(const float4*)&b[lane * 4];
    ushort4 r;
    r.x = f2b(fmaxf((a0[0] + a1[0]) + (a2[0] + a3[0]) + bv.x, 0.f));
    r.y = f2b(fmaxf((a0[1] + a1[1]) + (a2[1] + a3[1]) + bv.y, 0.f));
    r.z = f2b(fmaxf((a0[2] + a1[2]) + (a2[2] + a3[2]) + bv.z, 0.f));
    r.w = f2b(fmaxf((a0[3] + a1[3]) + (a2[3] + a3[3]) + bv.w, 0.f));
    *(ushort4*)&out[(size_t)v * HID + lane * 4] = r;
}

// ---------------- final readout (bf16 h) ----------------
__global__ void k_final(const unsigned short* __restrict__ h, const int* __restrict__ mask,
                        const float* __restrict__ Wr, const float* __restrict__ br,
                        float* __restrict__ out) {
    int t = blockIdx.x;
    int lane = threadIdx.x;
    int node = mask[t];
    ushort2 hv = *(const ushort2*)&h[(size_t)node * HID + lane * 2];
    float h0 = b2f(hv.x), h1 = b2f(hv.y);
#pragma unroll
    for (int j = 0; j < OUTD; ++j) {
        float p = h0 * Wr[(lane * 2) * OUTD + j] + h1 * Wr[(lane * 2 + 1) * OUTD + j];
#pragma unroll
        for (int off = 32; off > 0; off >>= 1) p += __shfl_down(p, off);
        if (lane == 0) out[t * OUTD + j] = p + br[j];
    }
}

extern "C" void kernel_launch(void* const* d_in, const int* in_sizes, int n_in,
                              void* d_out, int out_size, void* d_ws, size_t ws_size,
                              hipStream_t stream) {
    const float* x  = (const float*)d_in[0];
    const int*   ei = (const int*)d_in[1];
    const int*   tm = (const int*)d_in[2];
    const float* W1 = (const float*)d_in[3];
    const float* b1 = (const float*)d_in[4];
    const float* W2 = (const float*)d_in[5];
    const float* b2 = (const float*)d_in[6];
    const float* Wr = (const float*)d_in[7];
    const float* br = (const float*)d_in[8];
    float* out = (float*)d_out;

    const int* e_src = ei;
    const int* e_dst = ei + N_EDGES;

    // workspace layout — all ranges disjoint (see R4 postmortem):
    char* ws = (char*)d_ws;
    float*          dinv     = (float*)(ws + 0x000000);
    int*            counts   = (int*)  (ws + 0x040000);
    int*            rowptr   = (int*)  (ws + 0x080000);
    int*            cursor   = (int*)  (ws + 0x0C0000);
    int*            partials = (int*)  (ws + 0x0F8000);
    int*            col      = (int*)  (ws + 0x100000);
    unsigned short* Wt1      = (unsigned short*)(ws + 0x410000);
    unsigned short* Wt2      = (unsigned short*)(ws + 0x430000);
    unsigned short* bufA     = (unsigned short*)(ws + 0x500000);   // 12.8 MB bf16
    unsigned short* bufB     = (unsigned short*)(ws + 0x1200000);  // 12.8 MB bf16

    const int NE4     = N_EDGES / 4;                     // 200000 (divides evenly)
    const int NB_EP   = ((NE4 + 255) / 256) * NPART;     // vectorized edge kernels
    const int NB_AGG  = (N_NODES * 32 + 255) / 256;
    const int NB_MF   = (N_NODES + 63) / 64;
    const int NB_SORT = (N_NODES + 3) / 4;

    // ---- prelude + CSR build (wide grids, XCD-partitioned) ----
    k_prelude<<<SCAN_NB, 256, 0, stream>>>(counts, W1, Wt1, W2, Wt2);
    k_hist<<<NB_EP, 256, 0, stream>>>(e_dst, counts, NE4);
    k_scan_part<<<SCAN_NB, 256, 0, stream>>>(counts, partials);
    k_scan_top<<<1, 256, 0, stream>>>(partials);
    k_scan_final<<<SCAN_NB, 256, 0, stream>>>(counts, partials, rowptr, cursor, dinv);
    k_fill<<<NB_EP, 256, 0, stream>>>(e_src, e_dst, cursor, col, NE4);
    k_sort_rows<<<NB_SORT, 256, 0, stream>>>(rowptr, counts, col);

    // ---- layer 1 ----
    k_gemm_mfma<EMBED, false><<<NB_MF, 256, 0, stream>>>(x, Wt1, bufA, N_NODES);
    k_agg_csr<<<NB_AGG, 256, 0, stream>>>(bufA, rowptr, counts, col, dinv, b1, bufB);

    // ---- layer 2 ----
    k_gemm_mfma<HID, true><<<NB_MF, 256, 0, stream>>>(bufB, Wt2, bufA, N_NODES);
    k_agg_csr<<<NB_AGG, 256, 0, stream>>>(bufA, rowptr, counts, col, dinv, b2, bufB);

    // ---- readout ----
    k_final<<<N_TGT, 64, 0, stream>>>(bufB, tm, Wr, br, out);
}